// Round 1
// baseline (313.350 us; speedup 1.0000x reference)
//
#include <hip/hip_runtime.h>
#include <hip/hip_bf16.h>
#include <math.h>

typedef __attribute__((ext_vector_type(8))) short bf16x8;
typedef __attribute__((ext_vector_type(4))) float f32x4;

#define NBAG 128
#define MM 16
#define LL 120
#define WEMB 50
#define PEMB 5
#define OC 230
#define RR 53
#define DD 60

#define XPAD 72     // bf16 row stride for x tile (144B, 16B-aligned, odd bank phase)
#define XROWS 132   // rows -2..121 stored at +2, plus zero tail for padded t up to 127
#define BPAD 200    // bf16 row stride for B^T tile (400B, 16B-aligned)
#define KP 192      // K padded: 3 kh * 64
#define NP 256      // OC padded to 256

// ---------------- kernel 0: q[r][d] = sum_c r_embed[r][c] * att_W[r][c][d] ----------------
__global__ void q_kernel(const float* __restrict__ re, const float* __restrict__ attW,
                         float* __restrict__ q) {
    int r = blockIdx.x;
    int d = threadIdx.x;
    if (d < OC) {
        const float* Wr = attW + (size_t)r * OC * OC;
        const float* rer = re + r * OC;
        float acc = 0.f;
        for (int c = 0; c < OC; ++c) acc += rer[c] * Wr[c * OC + d];
        q[r * OC + d] = acc;
    }
}

// ---------------- kernel 1: fused embed + conv(im2col GEMM) + maxpool + bias + tanh ----------------
__global__ __launch_bounds__(512, 2) void conv_kernel(
    const int* __restrict__ wid, const int* __restrict__ p1, const int* __restrict__ p2,
    const float* __restrict__ w2v, const float* __restrict__ pemb,
    const float* __restrict__ cw, const float* __restrict__ cb,
    float* __restrict__ feat)
{
    __shared__ __hip_bfloat16 xs[2][XROWS * XPAD];   // 2 sentences, padded token matrix
    __shared__ __hip_bfloat16 bs[NP * BPAD];         // B^T: bs[oc][kh*64+d]
    int tid = threadIdx.x;

    // stage B^T (all 512 threads)
    for (int idx = tid; idx < NP * KP; idx += 512) {
        int oc = idx / KP;
        int kk = idx - oc * KP;
        int kh = kk >> 6;
        int d = kk & 63;
        float v = (oc < OC && d < DD) ? cw[oc * (3 * DD) + kh * DD + d] : 0.f;
        bs[oc * BPAD + kk] = __float2bfloat16(v);
    }

    // zero x tiles (half the threads per sentence)
    int si = tid >> 8;     // 0 or 1
    int t2 = tid & 255;
    int sid = blockIdx.x * 2 + si;
    for (int i = t2; i < XROWS * XPAD; i += 256) xs[si][i] = __float2bfloat16(0.f);
    __syncthreads();

    // gather embeddings into rows 2..121, cols 0..59
    const int ibase = sid * LL;
    for (int s = t2; s < LL * DD; s += 256) {
        int j = s / DD;
        int d = s - j * DD;
        float v;
        if (d < WEMB)            v = w2v[(size_t)wid[ibase + j] * WEMB + d];
        else if (d < WEMB + PEMB) v = pemb[p1[ibase + j] * PEMB + (d - WEMB)];
        else                      v = pemb[p2[ibase + j] * PEMB + (d - WEMB - PEMB)];
        xs[si][(j + 2) * XPAD + d] = __float2bfloat16(v);
    }
    __syncthreads();

    // GEMM: each wave owns sentence (wave>>2), oc range [(wave&3)*64, +64)
    int wave = tid >> 6;
    int lane = tid & 63;
    int wsi = wave >> 2;
    int nb = (wave & 3) * 64;
    int lr = lane & 15;   // A row-in-tile / B col-in-tile
    int lh = lane >> 4;   // k-subgroup

    f32x4 acc[8][4];
    #pragma unroll
    for (int a = 0; a < 8; ++a)
        #pragma unroll
        for (int b = 0; b < 4; ++b) acc[a][b] = (f32x4){0.f, 0.f, 0.f, 0.f};

    const __hip_bfloat16* xbase = xs[wsi];
    #pragma unroll
    for (int ks = 0; ks < 6; ++ks) {
        int k = ks * 32 + lh * 8;
        int kh = k >> 6;
        int d = k & 63;
        bf16x8 bfrag[4];
        #pragma unroll
        for (int nt = 0; nt < 4; ++nt) {
            int n = nb + nt * 16 + lr;
            bfrag[nt] = *(const bf16x8*)&bs[n * BPAD + k];
        }
        #pragma unroll
        for (int mt = 0; mt < 8; ++mt) {
            int xrow = mt * 16 + lr + kh;   // t + kh (x stored with +2 offset = conv pad)
            bf16x8 afrag = *(const bf16x8*)&xbase[xrow * XPAD + d];
            #pragma unroll
            for (int nt = 0; nt < 4; ++nt)
                acc[mt][nt] = __builtin_amdgcn_mfma_f32_16x16x32_bf16(afrag, bfrag[nt], acc[mt][nt], 0, 0, 0);
        }
    }

    // epilogue: masked max over t<122, shuffle-reduce across row groups, bias + tanh
    int out_sid = blockIdx.x * 2 + wsi;
    #pragma unroll
    for (int nt = 0; nt < 4; ++nt) {
        float mx = -1e30f;
        #pragma unroll
        for (int mt = 0; mt < 8; ++mt) {
            #pragma unroll
            for (int r = 0; r < 4; ++r) {
                int t = mt * 16 + lh * 4 + r;
                if (t < 122) mx = fmaxf(mx, acc[mt][nt][r]);
            }
        }
        mx = fmaxf(mx, __shfl_xor(mx, 16));
        mx = fmaxf(mx, __shfl_xor(mx, 32));
        int oc = nb + nt * 16 + lr;
        if (lane < 16 && oc < OC)
            feat[(size_t)out_sid * OC + oc] = tanhf(mx + cb[oc]);
    }
}

// ---------------- kernel 2: per-bag attention + logits + log-softmax + max over r ----------------
__global__ __launch_bounds__(512) void bag_kernel(
    const float* __restrict__ feat, const float* __restrict__ q,
    const float* __restrict__ re, const float* __restrict__ rb,
    float* __restrict__ out)
{
    __shared__ float fs[MM * OC];      // feat for this bag
    __shared__ float sc[RR * MM];      // scores -> att (in place)
    __shared__ float ss[RR * OC];      // s = att @ feat * 0.5
    __shared__ float lg[RR * 56];      // logits padded
    __shared__ float lse[RR];
    int b = blockIdx.x, tid = threadIdx.x;

    for (int i = tid; i < MM * OC; i += 512) fs[i] = feat[(size_t)b * MM * OC + i];
    __syncthreads();

    // scores[r][m] = q[r] . feat[m]
    for (int idx = tid; idx < RR * MM; idx += 512) {
        int r = idx >> 4, m = idx & 15;
        const float* qr = q + r * OC;
        const float* fm = fs + m * OC;
        float a = 0.f;
        for (int d = 0; d < OC; ++d) a += qr[d] * fm[d];
        sc[idx] = a;
    }
    __syncthreads();

    // softmax over m
    if (tid < RR) {
        float mx = -1e30f;
        #pragma unroll
        for (int m = 0; m < MM; ++m) mx = fmaxf(mx, sc[tid * MM + m]);
        float s = 0.f, e[MM];
        #pragma unroll
        for (int m = 0; m < MM; ++m) { e[m] = expf(sc[tid * MM + m] - mx); s += e[m]; }
        float inv = 1.f / s;
        #pragma unroll
        for (int m = 0; m < MM; ++m) sc[tid * MM + m] = e[m] * inv;
    }
    __syncthreads();

    // s[r][c] = 0.5 * sum_m att[r][m] * feat[m][c]
    for (int idx = tid; idx < RR * OC; idx += 512) {
        int r = idx / OC, c = idx - r * OC;
        float a = 0.f;
        #pragma unroll
        for (int m = 0; m < MM; ++m) a += sc[r * MM + m] * fs[m * OC + c];
        ss[idx] = 0.5f * a;
    }
    __syncthreads();

    // logits[r][s2] = s[r] . re[s2] + rb[s2]
    for (int idx = tid; idx < RR * RR; idx += 512) {
        int r = idx / RR, s2 = idx - r * RR;
        const float* sr = ss + r * OC;
        const float* res = re + s2 * OC;
        float a = 0.f;
        for (int d = 0; d < OC; ++d) a += sr[d] * res[d];
        lg[r * 56 + s2] = a + rb[s2];
    }
    __syncthreads();

    // lse per attention-row r
    if (tid < RR) {
        float mx = -1e30f;
        for (int s2 = 0; s2 < RR; ++s2) mx = fmaxf(mx, lg[tid * 56 + s2]);
        float s = 0.f;
        for (int s2 = 0; s2 < RR; ++s2) s += expf(lg[tid * 56 + s2] - mx);
        lse[tid] = mx + logf(s);
    }
    __syncthreads();

    // pred[b][s2] = max_r (logits[r][s2] - lse[r])
    if (tid < RR) {
        float mx = -1e30f;
        for (int r = 0; r < RR; ++r) mx = fmaxf(mx, lg[r * 56 + tid] - lse[r]);
        out[b * RR + tid] = mx;
    }
}

extern "C" void kernel_launch(void* const* d_in, const int* in_sizes, int n_in,
                              void* d_out, int out_size, void* d_ws, size_t ws_size,
                              hipStream_t stream) {
    const int* wid   = (const int*)d_in[0];
    const int* p1    = (const int*)d_in[1];
    const int* p2    = (const int*)d_in[2];
    const float* w2v = (const float*)d_in[3];
    const float* pe  = (const float*)d_in[4];
    const float* cw  = (const float*)d_in[5];
    const float* cb  = (const float*)d_in[6];
    const float* re  = (const float*)d_in[7];
    const float* rb  = (const float*)d_in[8];
    const float* attW= (const float*)d_in[9];
    float* out = (float*)d_out;

    float* q    = (float*)d_ws;                          // 53*230*4 = 48.8 KB
    float* feat = (float*)((char*)d_ws + (64 << 10));    // 2048*230*4 = 1.88 MB

    q_kernel<<<RR, 256, 0, stream>>>(re, attW, q);
    conv_kernel<<<1024, 512, 0, stream>>>(wid, p1, p2, w2v, pe, cw, cb, feat);
    bag_kernel<<<NBAG, 512, 0, stream>>>(feat, q, re, rb, out);
}

// Round 2
// 169.602 us; speedup vs baseline: 1.8476x; 1.8476x over previous
//
#include <hip/hip_runtime.h>
#include <hip/hip_bf16.h>
#include <math.h>

typedef __attribute__((ext_vector_type(8))) short bf16x8;
typedef __attribute__((ext_vector_type(4))) short short4v;
typedef __attribute__((ext_vector_type(4))) float f32x4;

#define NBAG 128
#define MM 16
#define LL 120
#define WEMB 50
#define PEMB 5
#define OC 230
#define RR 53
#define DD 60

#define XPAD 72     // bf16 row stride (144B, 16B-aligned)
#define XROWS 132   // rows -2..121 stored at +2, zero tail to row 131

// ---- kernel P: pre-convert conv weights to bf16 in MFMA-fragment order ----
// frag index f = ((oq*6+ks)*4+nt); element = wsB[(f*64+lane)*8 + e]
// maps to oc = oq*64+nt*16+(lane&15), k = ks*32+(lane>>4)*8+e; kh=k>>6, d=k&63
__global__ void prep_kernel(const float* __restrict__ cw, __hip_bfloat16* __restrict__ wsB) {
    int t = blockIdx.x * 256 + threadIdx.x;       // one thread per 8-elem fragment slot
    if (t >= 4 * 6 * 4 * 64) return;
    int lane = t & 63;
    int frag = t >> 6;
    int nt = frag & 3;
    int rem = frag >> 2;
    int ks = rem % 6;
    int oq = rem / 6;
    int oc = oq * 64 + nt * 16 + (lane & 15);
    int k0 = ks * 32 + (lane >> 4) * 8;
    bf16x8 o;
    #pragma unroll
    for (int e = 0; e < 8; ++e) {
        int k = k0 + e, kh = k >> 6, d = k & 63;
        float v = (oc < OC && d < DD) ? cw[oc * (3 * DD) + kh * DD + d] : 0.f;
        __hip_bfloat16 b = __float2bfloat16(v);
        o[e] = *reinterpret_cast<short*>(&b);
    }
    ((bf16x8*)wsB)[t] = o;
}

// ---- kernel Q: q[r][d] = sum_c r_embed[r][c] * att_W[r][c][d] ----
__global__ void q_kernel(const float* __restrict__ re, const float* __restrict__ attW,
                         float* __restrict__ q) {
    int r = blockIdx.x >> 2;
    int d = (blockIdx.x & 3) * 64 + threadIdx.x;
    if (d >= OC) return;
    const float* Wr = attW + (size_t)r * OC * OC + d;
    const float* rer = re + r * OC;
    float a0 = 0.f, a1 = 0.f;
    for (int c = 0; c < OC; c += 2) {
        a0 += rer[c]     * Wr[(size_t)c * OC];
        a1 += rer[c + 1] * Wr[(size_t)(c + 1) * OC];
    }
    q[r * OC + d] = a0 + a1;
}

// ---- kernel C: fused embed + conv(im2col GEMM) + maxpool + bias + tanh ----
// 1 sentence per block; wave w: oq = w>>1 (64-oc quarter), th = w&1 (64-t half)
__global__ __launch_bounds__(512, 3) void conv_kernel(
    const int* __restrict__ wid, const int* __restrict__ p1, const int* __restrict__ p2,
    const float* __restrict__ w2v, const float* __restrict__ pemb,
    const __hip_bfloat16* __restrict__ wsB, const float* __restrict__ cb,
    float* __restrict__ feat)
{
    __shared__ __hip_bfloat16 xs[XROWS * XPAD];
    __shared__ float sm[2][256];
    int tid = threadIdx.x;
    int sid = blockIdx.x;
    int lane = tid & 63, wave = tid >> 6;
    int oq = wave >> 1, th = wave & 1;
    int lr = lane & 15, lh = lane >> 4;

    // zero ONLY pad regions (disjoint from gather writes -> single barrier)
    // (a) rows 0,1,122..131 full width: 12 rows x 9 x 16B
    for (int i = tid; i < 108; i += 512) {
        int rr = i / 9, cc = (i - rr * 9) * 8;
        int row = (rr < 2) ? rr : 120 + rr;
        *(bf16x8*)&xs[row * XPAD + cc] = (bf16x8){0,0,0,0,0,0,0,0};
    }
    // (b) rows 2..121, cols 60..71
    for (int i = tid; i < 120; i += 512) {
        int row = 2 + i;
        *(short4v*)&xs[row * XPAD + 60] = (short4v){0,0,0,0};
        *(bf16x8*)&xs[row * XPAD + 64] = (bf16x8){0,0,0,0,0,0,0,0};
    }
    // gather embeddings into rows 2..121, cols 0..59
    const int base = sid * LL;
    for (int s = tid; s < LL * DD; s += 512) {
        int j = s / DD, d = s - j * DD;
        float v;
        if (d < WEMB)              v = w2v[(size_t)wid[base + j] * WEMB + d];
        else if (d < WEMB + PEMB)  v = pemb[p1[base + j] * PEMB + (d - WEMB)];
        else                       v = pemb[p2[base + j] * PEMB + (d - WEMB - PEMB)];
        xs[(j + 2) * XPAD + d] = __float2bfloat16(v);
    }
    __syncthreads();

    f32x4 acc[4][4];
    #pragma unroll
    for (int a = 0; a < 4; ++a)
        #pragma unroll
        for (int b = 0; b < 4; ++b) acc[a][b] = (f32x4){0.f, 0.f, 0.f, 0.f};

    const bf16x8* wb = (const bf16x8*)wsB;
    #pragma unroll
    for (int ks = 0; ks < 6; ++ks) {
        bf16x8 bfrag[4];
        #pragma unroll
        for (int nt = 0; nt < 4; ++nt)
            bfrag[nt] = wb[((oq * 6 + ks) * 4 + nt) * 64 + lane];
        int k = ks * 32 + lh * 8;
        int kh = k >> 6, d = k & 63;
        #pragma unroll
        for (int mt = 0; mt < 4; ++mt) {
            int xrow = th * 64 + mt * 16 + lr + kh;   // +2 pad built into storage offset
            bf16x8 af = *(const bf16x8*)&xs[xrow * XPAD + d];
            #pragma unroll
            for (int nt = 0; nt < 4; ++nt)
                acc[mt][nt] = __builtin_amdgcn_mfma_f32_16x16x32_bf16(af, bfrag[nt], acc[mt][nt], 0, 0, 0);
        }
    }

    // masked max over this wave's 64 t, reduce across lh groups, stash per-th partial
    #pragma unroll
    for (int nt = 0; nt < 4; ++nt) {
        float mx = -1e30f;
        #pragma unroll
        for (int mt = 0; mt < 4; ++mt) {
            #pragma unroll
            for (int r = 0; r < 4; ++r) {
                int t = th * 64 + mt * 16 + lh * 4 + r;
                if (t < 122) mx = fmaxf(mx, acc[mt][nt][r]);
            }
        }
        mx = fmaxf(mx, __shfl_xor(mx, 16));
        mx = fmaxf(mx, __shfl_xor(mx, 32));
        if (lane < 16) sm[th][oq * 64 + nt * 16 + lr] = mx;
    }
    __syncthreads();
    if (tid < OC)
        feat[(size_t)sid * OC + tid] = tanhf(fmaxf(sm[0][tid], sm[1][tid]) + cb[tid]);
}

// ---- kernel B: per-bag attention + logits + log-softmax + max over r ----
__global__ __launch_bounds__(512) void bag_kernel(
    const float* __restrict__ feat, const float* __restrict__ q,
    const float* __restrict__ re, const float* __restrict__ rb,
    float* __restrict__ out)
{
    __shared__ float fs[MM * OC];
    __shared__ float sc[RR * MM];
    __shared__ float ss[RR * OC];
    __shared__ float lg[RR * 56];
    __shared__ float lse[RR];
    int b = blockIdx.x, tid = threadIdx.x;

    for (int i = tid; i < MM * OC; i += 512) fs[i] = feat[(size_t)b * MM * OC + i];
    __syncthreads();

    for (int idx = tid; idx < RR * MM; idx += 512) {
        int r = idx >> 4, m = idx & 15;
        const float* qr = q + r * OC;
        const float* fm = fs + m * OC;
        float a = 0.f;
        for (int d = 0; d < OC; ++d) a += qr[d] * fm[d];
        sc[idx] = a;
    }
    __syncthreads();

    if (tid < RR) {
        float mx = -1e30f;
        #pragma unroll
        for (int m = 0; m < MM; ++m) mx = fmaxf(mx, sc[tid * MM + m]);
        float s = 0.f, e[MM];
        #pragma unroll
        for (int m = 0; m < MM; ++m) { e[m] = expf(sc[tid * MM + m] - mx); s += e[m]; }
        float inv = 1.f / s;
        #pragma unroll
        for (int m = 0; m < MM; ++m) sc[tid * MM + m] = e[m] * inv;
    }
    __syncthreads();

    for (int idx = tid; idx < RR * OC; idx += 512) {
        int r = idx / OC, c = idx - r * OC;
        float a = 0.f;
        #pragma unroll
        for (int m = 0; m < MM; ++m) a += sc[r * MM + m] * fs[m * OC + c];
        ss[idx] = 0.5f * a;
    }
    __syncthreads();

    // logits: consecutive lanes -> consecutive r, re[s2] row is broadcast
    for (int idx = tid; idx < RR * RR; idx += 512) {
        int s2 = idx / RR, r = idx - s2 * RR;
        const float* sr = ss + r * OC;
        const float* res = re + s2 * OC;
        float a = 0.f;
        for (int d = 0; d < OC; ++d) a += sr[d] * res[d];
        lg[r * 56 + s2] = a + rb[s2];
    }
    __syncthreads();

    if (tid < RR) {
        float mx = -1e30f;
        for (int s2 = 0; s2 < RR; ++s2) mx = fmaxf(mx, lg[tid * 56 + s2]);
        float s = 0.f;
        for (int s2 = 0; s2 < RR; ++s2) s += expf(lg[tid * 56 + s2] - mx);
        lse[tid] = mx + logf(s);
    }
    __syncthreads();

    if (tid < RR) {
        float mx = -1e30f;
        for (int r = 0; r < RR; ++r) mx = fmaxf(mx, lg[r * 56 + tid] - lse[r]);
        out[b * RR + tid] = mx;
    }
}

extern "C" void kernel_launch(void* const* d_in, const int* in_sizes, int n_in,
                              void* d_out, int out_size, void* d_ws, size_t ws_size,
                              hipStream_t stream) {
    const int* wid   = (const int*)d_in[0];
    const int* p1    = (const int*)d_in[1];
    const int* p2    = (const int*)d_in[2];
    const float* w2v = (const float*)d_in[3];
    const float* pe  = (const float*)d_in[4];
    const float* cw  = (const float*)d_in[5];
    const float* cb  = (const float*)d_in[6];
    const float* re  = (const float*)d_in[7];
    const float* rb  = (const float*)d_in[8];
    const float* attW= (const float*)d_in[9];
    float* out = (float*)d_out;

    float* q            = (float*)d_ws;                           // 48,760 B
    __hip_bfloat16* wsB = (__hip_bfloat16*)((char*)d_ws + 49152); // 98,304 B
    float* feat         = (float*)((char*)d_ws + 147456);         // 1,884,160 B

    prep_kernel<<<24, 256, 0, stream>>>(cw, wsB);
    q_kernel<<<RR * 4, 64, 0, stream>>>(re, attW, q);
    conv_kernel<<<NBAG * MM, 512, 0, stream>>>(wid, p1, p2, w2v, pe, wsB, cb, feat);
    bag_kernel<<<NBAG, 512, 0, stream>>>(feat, q, re, rb, out);
}

// Round 3
// 87.113 us; speedup vs baseline: 3.5970x; 1.9469x over previous
//
#include <hip/hip_runtime.h>
#include <hip/hip_bf16.h>
#include <math.h>

typedef __attribute__((ext_vector_type(8))) short bf16x8;
typedef __attribute__((ext_vector_type(4))) float f32x4;

#define NBAG 128
#define MM 16
#define LL 120
#define WEMB 50
#define PEMB 5
#define OC 230
#define RR 53
#define DD 60

#define XPAD 72        // bf16 row stride for x tile (144 B)
#define XROWSG 124     // rows stored in global x: -2..121 at +2 offset
#define XROWS 132      // LDS rows (124..131 garbage, only masked t reads them)
#define XSBYTES (XROWSG * XPAD * 2)   // 17856 B per sentence, 16B-multiple
#define FSTRIDE 280    // feat16 row stride (560 B): conflict-free b128 reads
#define KP2 256        // scores-GEMM K (230 padded)

static __device__ __forceinline__ short f2bf(float v) {
    __hip_bfloat16 b = __float2bfloat16(v);
    return *reinterpret_cast<short*>(&b);
}

static __device__ __forceinline__ void gload_lds16(const void* g, void* l) {
    __builtin_amdgcn_global_load_lds(
        (const __attribute__((address_space(1))) void*)g,
        (__attribute__((address_space(3))) void*)l, 16, 0, 0);
}

// ---- kernel P: conv weights -> bf16 MFMA-fragment order ----
__global__ void prep_kernel(const float* __restrict__ cw, __hip_bfloat16* __restrict__ wsB) {
    int t = blockIdx.x * 256 + threadIdx.x;
    if (t >= 4 * 6 * 4 * 64) return;
    int lane = t & 63, frag = t >> 6;
    int nt = frag & 3, rem = frag >> 2;
    int ks = rem % 6, oq = rem / 6;
    int oc = oq * 64 + nt * 16 + (lane & 15);
    int k0 = ks * 32 + (lane >> 4) * 8;
    bf16x8 o;
    #pragma unroll
    for (int e = 0; e < 8; ++e) {
        int k = k0 + e, kh = k >> 6, d = k & 63;
        float v = (oc < OC && d < DD) ? cw[oc * (3 * DD) + kh * DD + d] : 0.f;
        o[e] = f2bf(v);
    }
    ((bf16x8*)wsB)[t] = o;
}

// ---- kernel Q: q[r][d] = sum_c re[r][c]*attW[r][c][d], coalesced + c-split ----
__global__ __launch_bounds__(1024) void q_kernel(const float* __restrict__ re,
                                                 const float* __restrict__ attW,
                                                 float* __restrict__ q) {
    __shared__ float part[4][256];
    int r = blockIdx.x;
    int cc = threadIdx.x >> 8;          // 0..3
    int d  = threadIdx.x & 255;
    int c0 = cc * 58, c1 = min(OC, c0 + 58);
    const float* W = attW + (size_t)r * OC * OC;
    const float* rer = re + r * OC;
    float acc = 0.f;
    if (d < OC)
        for (int c = c0; c < c1; ++c) acc += rer[c] * W[(size_t)c * OC + d];
    part[cc][d] = acc;
    __syncthreads();
    if (cc == 0 && d < OC)
        q[r * OC + d] = part[0][d] + part[1][d] + part[2][d] + part[3][d];
}

// ---- kernel P2: pack B2[256][128] bf16 frags: cols 0..52 = q rows, 64..116 = re rows ----
__global__ void pack2_kernel(const float* __restrict__ qf, const float* __restrict__ re,
                             __hip_bfloat16* __restrict__ wsB2) {
    int t = blockIdx.x * 256 + threadIdx.x;
    if (t >= 8 * 8 * 64) return;
    int lane = t & 63, f = t >> 6;
    int ks = f >> 3, nt = f & 7;
    int col = nt * 16 + (lane & 15);
    int k0 = ks * 32 + (lane >> 4) * 8;
    bf16x8 o;
    #pragma unroll
    for (int e = 0; e < 8; ++e) {
        int k = k0 + e;
        float v = 0.f;
        if (k < OC) {
            if (col < RR)                      v = qf[col * OC + k];
            else if (col >= 64 && col < 64+RR) v = re[(col - 64) * OC + k];
        }
        o[e] = f2bf(v);
    }
    ((bf16x8*)wsB2)[t] = o;
}

// ---- kernel G: build padded bf16 token matrix x[sid][124 rows][72] in ws ----
__global__ void gather_kernel(const int* __restrict__ wid, const int* __restrict__ p1,
                              const int* __restrict__ p2, const float* __restrict__ w2v,
                              const float* __restrict__ pemb,
                              __hip_bfloat16* __restrict__ xg, int s0) {
    int row = threadIdx.x;
    if (row >= XROWSG) return;
    int sid = s0 + blockIdx.x;
    __hip_bfloat16* dst = xg + (size_t)blockIdx.x * (XROWSG * XPAD) + row * XPAD;
    if (row < 2 || row >= 122) {              // pad rows -> zeros
        #pragma unroll
        for (int jj = 0; jj < 9; ++jj) ((bf16x8*)dst)[jj] = (bf16x8){0,0,0,0,0,0,0,0};
        return;
    }
    int j = row - 2;
    int base = sid * LL + j;
    int w = wid[base], a1 = p1[base], a2 = p2[base];
    const float2* wr = (const float2*)(w2v + (size_t)w * WEMB);
    float2 wv[25];
    #pragma unroll
    for (int i = 0; i < 25; ++i) wv[i] = wr[i];
    float pv1[PEMB], pv2[PEMB];
    #pragma unroll
    for (int i = 0; i < PEMB; ++i) pv1[i] = pemb[a1 * PEMB + i];
    #pragma unroll
    for (int i = 0; i < PEMB; ++i) pv2[i] = pemb[a2 * PEMB + i];
    #pragma unroll
    for (int jj = 0; jj < 9; ++jj) {
        bf16x8 o;
        #pragma unroll
        for (int e = 0; e < 8; ++e) {
            int c = jj * 8 + e;
            float v;
            if (c < WEMB)            v = (c & 1) ? wv[c >> 1].y : wv[c >> 1].x;
            else if (c < WEMB+PEMB)  v = pv1[c - WEMB];
            else if (c < DD)         v = pv2[c - WEMB - PEMB];
            else                     v = 0.f;
            o[e] = f2bf(v);
        }
        ((bf16x8*)dst)[jj] = o;
    }
}

// ---- kernel C: conv GEMM (global_load_lds staging) + maxpool + bias + tanh -> feat bf16 ----
__global__ __launch_bounds__(512, 3) void conv_kernel(
    const __hip_bfloat16* __restrict__ xg,
    const __hip_bfloat16* __restrict__ wsB, const float* __restrict__ cb,
    __hip_bfloat16* __restrict__ feat16, int s0)
{
    __shared__ __hip_bfloat16 xs[XROWS * XPAD];
    __shared__ float sm[2][256];
    int tid = threadIdx.x;
    int lane = tid & 63, wave = tid >> 6;
    int oq = wave >> 1, th = wave & 1;
    int lr = lane & 15, lh = lane >> 4;

    // async stage x (17856 B, linear) into LDS
    const char* gx = (const char*)(xg + (size_t)blockIdx.x * (XROWSG * XPAD));
    char* lx = (char*)xs;
    #pragma unroll
    for (int i = 0; i < 3; ++i) {
        int off = i * 8192 + wave * 1024 + lane * 16;
        if (off < XSBYTES) gload_lds16(gx + off, lx + i * 8192 + wave * 1024);
    }
    __syncthreads();

    f32x4 acc[4][4];
    #pragma unroll
    for (int a = 0; a < 4; ++a)
        #pragma unroll
        for (int b = 0; b < 4; ++b) acc[a][b] = (f32x4){0.f, 0.f, 0.f, 0.f};

    const bf16x8* wb = (const bf16x8*)wsB;
    #pragma unroll
    for (int ks = 0; ks < 6; ++ks) {
        bf16x8 bfrag[4];
        #pragma unroll
        for (int nt = 0; nt < 4; ++nt)
            bfrag[nt] = wb[((oq * 6 + ks) * 4 + nt) * 64 + lane];
        int k = ks * 32 + lh * 8;
        int kh = k >> 6, d = k & 63;
        #pragma unroll
        for (int mt = 0; mt < 4; ++mt) {
            int xrow = th * 64 + mt * 16 + lr + kh;
            bf16x8 af = *(const bf16x8*)&xs[xrow * XPAD + d];
            #pragma unroll
            for (int nt = 0; nt < 4; ++nt)
                acc[mt][nt] = __builtin_amdgcn_mfma_f32_16x16x32_bf16(af, bfrag[nt], acc[mt][nt], 0, 0, 0);
        }
    }

    #pragma unroll
    for (int nt = 0; nt < 4; ++nt) {
        float mx = -1e30f;
        #pragma unroll
        for (int mt = 0; mt < 4; ++mt) {
            #pragma unroll
            for (int r = 0; r < 4; ++r) {
                int t = th * 64 + mt * 16 + lh * 4 + r;
                if (t < 122) mx = fmaxf(mx, acc[mt][nt][r]);
            }
        }
        mx = fmaxf(mx, __shfl_xor(mx, 16));
        mx = fmaxf(mx, __shfl_xor(mx, 32));
        if (lane < 16) sm[th][oq * 64 + nt * 16 + lr] = mx;
    }
    __syncthreads();
    if (tid < KP2) {
        int sid = s0 + blockIdx.x;
        float v = (tid < OC) ? tanhf(fmaxf(sm[0][tid], sm[1][tid]) + cb[tid]) : 0.f;
        feat16[(size_t)sid * FSTRIDE + tid] = __float2bfloat16(v);
    }
}

// ---- kernel B: per-bag scores GEMM (MFMA) + softmax + K=16 logits + log-softmax + max ----
__global__ __launch_bounds__(512) void bag_kernel(
    const __hip_bfloat16* __restrict__ feat16, const __hip_bfloat16* __restrict__ wsB2,
    const float* __restrict__ rb, float* __restrict__ out)
{
    __shared__ __hip_bfloat16 fA[MM * FSTRIDE];   // 8960 B
    __shared__ float scg[MM][132];                // scores(0..52) | G(64..116)
    __shared__ float att[RR][17];
    __shared__ float lg[RR * 56];
    __shared__ float lse[RR];
    int b = blockIdx.x, tid = threadIdx.x;
    int lane = tid & 63, wave = tid >> 6;
    int lr = lane & 15, lh = lane >> 4;

    // stage this bag's 16 feat rows (8960 B linear)
    const char* gf = (const char*)(feat16 + (size_t)b * MM * FSTRIDE);
    char* lf = (char*)fA;
    #pragma unroll
    for (int i = 0; i < 2; ++i) {
        int off = i * 8192 + wave * 1024 + lane * 16;
        if (off < MM * FSTRIDE * 2) gload_lds16(gf + off, lf + i * 8192 + wave * 1024);
    }
    __syncthreads();

    // scores GEMM: [16 x 256] @ B2[256 x 128]; wave w owns n-tile w
    f32x4 acc = (f32x4){0.f, 0.f, 0.f, 0.f};
    const bf16x8* wb2 = (const bf16x8*)wsB2;
    #pragma unroll
    for (int ks = 0; ks < 8; ++ks) {
        bf16x8 bfrag = wb2[(ks * 8 + wave) * 64 + lane];
        int k = ks * 32 + lh * 8;
        bf16x8 af = *(const bf16x8*)((const char*)fA + lr * (FSTRIDE * 2) + k * 2);
        acc = __builtin_amdgcn_mfma_f32_16x16x32_bf16(af, bfrag, acc, 0, 0, 0);
    }
    #pragma unroll
    for (int r = 0; r < 4; ++r) scg[lh * 4 + r][wave * 16 + lr] = acc[r];
    __syncthreads();

    // softmax over m for each attention row r
    if (tid < RR) {
        float mx = -1e30f;
        #pragma unroll
        for (int m = 0; m < MM; ++m) mx = fmaxf(mx, scg[m][tid]);
        float s = 0.f, e[MM];
        #pragma unroll
        for (int m = 0; m < MM; ++m) { e[m] = expf(scg[m][tid] - mx); s += e[m]; }
        float inv = 1.f / s;
        #pragma unroll
        for (int m = 0; m < MM; ++m) att[tid][m] = e[m] * inv;
    }
    __syncthreads();

    // logits[r][s2] = 0.5 * sum_m att[r][m] * G[m][s2] + rb[s2]
    for (int idx = tid; idx < RR * RR; idx += 512) {
        int r = idx % RR, s2 = idx / RR;
        float a = 0.f;
        #pragma unroll
        for (int m = 0; m < MM; ++m) a += att[r][m] * scg[m][64 + s2];
        lg[r * 56 + s2] = 0.5f * a + rb[s2];
    }
    __syncthreads();

    if (tid < RR) {
        float mx = -1e30f;
        for (int s2 = 0; s2 < RR; ++s2) mx = fmaxf(mx, lg[tid * 56 + s2]);
        float s = 0.f;
        for (int s2 = 0; s2 < RR; ++s2) s += expf(lg[tid * 56 + s2] - mx);
        lse[tid] = mx + logf(s);
    }
    __syncthreads();

    if (tid < RR) {
        float mx = -1e30f;
        for (int r = 0; r < RR; ++r) mx = fmaxf(mx, lg[r * 56 + tid] - lse[r]);
        out[b * RR + tid] = mx;
    }
}

extern "C" void kernel_launch(void* const* d_in, const int* in_sizes, int n_in,
                              void* d_out, int out_size, void* d_ws, size_t ws_size,
                              hipStream_t stream) {
    const int* wid   = (const int*)d_in[0];
    const int* p1    = (const int*)d_in[1];
    const int* p2    = (const int*)d_in[2];
    const float* w2v = (const float*)d_in[3];
    const float* pe  = (const float*)d_in[4];
    const float* cw  = (const float*)d_in[5];
    const float* cb  = (const float*)d_in[6];
    const float* re  = (const float*)d_in[7];
    const float* rb  = (const float*)d_in[8];
    const float* attW= (const float*)d_in[9];
    float* out = (float*)d_out;

    // ws layout
    float* qf            = (float*)d_ws;                                 // 48,760
    __hip_bfloat16* wsB  = (__hip_bfloat16*)((char*)d_ws + 49152);       // 98,304
    __hip_bfloat16* wsB2 = (__hip_bfloat16*)((char*)d_ws + 147456);      // 65,536
    __hip_bfloat16* f16  = (__hip_bfloat16*)((char*)d_ws + 212992);      // 2048*280*2 = 1,146,880
    char* xws            = (char*)d_ws + 1359872;

    prep_kernel<<<24, 256, 0, stream>>>(cw, wsB);
    q_kernel<<<RR, 1024, 0, stream>>>(re, attW, qf);
    pack2_kernel<<<16, 256, 0, stream>>>(qf, re, wsB2);

    size_t avail = (ws_size > 1359872) ? ws_size - 1359872 : 0;
    int chunk = (int)(avail / XSBYTES);
    if (chunk > 2048) chunk = 2048;
    if (chunk < 1) chunk = 1;   // assume ws_size is at least ~1.4 MB + one sentence
    for (int s0 = 0; s0 < NBAG * MM; s0 += chunk) {
        int n = NBAG * MM - s0; if (n > chunk) n = chunk;
        gather_kernel<<<n, 192, 0, stream>>>(wid, p1, p2, w2v, pe,
                                             (__hip_bfloat16*)xws, s0);
        conv_kernel<<<n, 512, 0, stream>>>((const __hip_bfloat16*)xws, wsB, cb, f16, s0);
    }
    bag_kernel<<<NBAG, 512, 0, stream>>>(f16, wsB2, rb, out);
}

// Round 4
// 69.155 us; speedup vs baseline: 4.5311x; 1.2597x over previous
//
#include <hip/hip_runtime.h>
#include <hip/hip_bf16.h>
#include <math.h>

typedef __attribute__((ext_vector_type(8))) short bf16x8;
typedef __attribute__((ext_vector_type(4))) float f32x4;

#define NBAG 128
#define MM 16
#define LL 120
#define WEMB 50
#define PEMB 5
#define OC 230
#define RR 53
#define DD 60

#define XPAD 72        // bf16 row stride for x tile (144 B)
#define XROWSG 124     // rows stored in global x: -2..121 at +2 offset
#define XROWS 132      // LDS rows (124..131 garbage, only masked t reads them)
#define XSBYTES (XROWSG * XPAD * 2)   // 17856 B per sentence
#define FSTRIDE 280    // feat16 row stride (560 B)
#define KP2 256        // scores-GEMM K (230 padded)

#define QBLOCKS 106    // 53 r x 2 c-halves
#define PREPB 12       // 12 x 512 = 6144 fragment slots
#define PACK2B 8       // 8 x 512 = 4096 fragment slots

static __device__ __forceinline__ short f2bf(float v) {
    __hip_bfloat16 b = __float2bfloat16(v);
    return *reinterpret_cast<short*>(&b);
}

static __device__ __forceinline__ void gload_lds16(const void* g, void* l) {
    __builtin_amdgcn_global_load_lds(
        (const __attribute__((address_space(1))) void*)g,
        (__attribute__((address_space(3))) void*)l, 16, 0, 0);
}

// ================= kernel A: prep | q | gather (heterogeneous) =================
__global__ __launch_bounds__(512) void kernelA(
    const int* __restrict__ wid, const int* __restrict__ p1, const int* __restrict__ p2,
    const float* __restrict__ w2v, const float* __restrict__ pemb,
    const float* __restrict__ cw, const float* __restrict__ attW,
    const float* __restrict__ re,
    __hip_bfloat16* __restrict__ wsB, float* __restrict__ qf,
    __hip_bfloat16* __restrict__ xg, int gather_n, int s0, int first)
{
    __shared__ float part[2][256];
    int tid = threadIdx.x;
    int bid = blockIdx.x;

    if (first && bid < PREPB) {
        // ---- prep: conv weights -> bf16 MFMA-fragment order ----
        int t = bid * 512 + tid;
        if (t >= 4 * 6 * 4 * 64) return;
        int lane = t & 63, frag = t >> 6;
        int nt = frag & 3, rem = frag >> 2;
        int ks = rem % 6, oq = rem / 6;
        int oc = oq * 64 + nt * 16 + (lane & 15);
        int k0 = ks * 32 + (lane >> 4) * 8;
        bf16x8 o;
        #pragma unroll
        for (int e = 0; e < 8; ++e) {
            int k = k0 + e, kh = k >> 6, d = k & 63;
            float v = (oc < OC && d < DD) ? cw[oc * (3 * DD) + kh * DD + d] : 0.f;
            o[e] = f2bf(v);
        }
        ((bf16x8*)wsB)[t] = o;
        return;
    }
    if (first && bid < PREPB + QBLOCKS) {
        // ---- q partial: qf[half][r][d] = sum_{c in half} re[r][c]*attW[r][c][d] ----
        int qb = bid - PREPB;
        int r = qb >> 1, half = qb & 1;
        int lh2 = tid >> 8, d = tid & 255;
        int c0 = half * 116 + lh2 * 58;
        int c1 = min(OC, c0 + 58);
        const float* W = attW + (size_t)r * OC * OC;
        const float* rer = re + r * OC;
        float acc = 0.f;
        if (d < OC)
            for (int c = c0; c < c1; ++c) acc += rer[c] * W[(size_t)c * OC + d];
        part[lh2][d] = acc;
        __syncthreads();
        if (lh2 == 0 && d < OC)
            qf[half * (RR * OC) + r * OC + d] = part[0][d] + part[1][d];
        return;
    }

    // ---- gather: 4 sentences per block, one padded row per thread ----
    int g = bid - (first ? (PREPB + QBLOCKS) : 0);
    int sl = tid >> 7;           // sentence within block
    int row = tid & 127;
    int slot = g * 4 + sl;
    if (slot >= gather_n || row >= XROWSG) return;
    int sid = s0 + slot;
    __hip_bfloat16* dst = xg + (size_t)slot * (XROWSG * XPAD) + row * XPAD;
    if (row < 2 || row >= 122) {
        #pragma unroll
        for (int jj = 0; jj < 9; ++jj) ((bf16x8*)dst)[jj] = (bf16x8){0,0,0,0,0,0,0,0};
        return;
    }
    int j = row - 2;
    int base = sid * LL + j;
    int w = wid[base], a1 = p1[base], a2 = p2[base];
    const float2* wr = (const float2*)(w2v + (size_t)w * WEMB);
    float2 wv[25];
    #pragma unroll
    for (int i = 0; i < 25; ++i) wv[i] = wr[i];
    float pv1[PEMB], pv2[PEMB];
    #pragma unroll
    for (int i = 0; i < PEMB; ++i) pv1[i] = pemb[a1 * PEMB + i];
    #pragma unroll
    for (int i = 0; i < PEMB; ++i) pv2[i] = pemb[a2 * PEMB + i];
    #pragma unroll
    for (int jj = 0; jj < 9; ++jj) {
        bf16x8 o;
        #pragma unroll
        for (int e = 0; e < 8; ++e) {
            int c = jj * 8 + e;
            float v;
            if (c < WEMB)            v = (c & 1) ? wv[c >> 1].y : wv[c >> 1].x;
            else if (c < WEMB+PEMB)  v = pv1[c - WEMB];
            else if (c < DD)         v = pv2[c - WEMB - PEMB];
            else                     v = 0.f;
            o[e] = f2bf(v);
        }
        ((bf16x8*)dst)[jj] = o;
    }
}

// ================= kernel B: pack2 | conv (heterogeneous) =================
__global__ __launch_bounds__(512, 3) void kernelB(
    const __hip_bfloat16* __restrict__ xg,
    const __hip_bfloat16* __restrict__ wsB, const float* __restrict__ cb,
    const float* __restrict__ qf, const float* __restrict__ re,
    __hip_bfloat16* __restrict__ wsB2,
    __hip_bfloat16* __restrict__ feat16, int s0, int first)
{
    __shared__ __hip_bfloat16 xs[XROWS * XPAD];
    __shared__ float sm[2][256];
    int tid = threadIdx.x;
    int bid = blockIdx.x;

    if (first && bid < PACK2B) {
        // ---- pack2: B2[256][128] frags: cols 0..52 = q rows, 64..116 = re rows ----
        int t = bid * 512 + tid;
        int lane = t & 63, f = t >> 6;
        int ks = f >> 3, nt = f & 7;
        int col = nt * 16 + (lane & 15);
        int k0 = ks * 32 + (lane >> 4) * 8;
        bf16x8 o;
        #pragma unroll
        for (int e = 0; e < 8; ++e) {
            int k = k0 + e;
            float v = 0.f;
            if (k < OC) {
                if (col < RR)
                    v = qf[col * OC + k] + qf[RR * OC + col * OC + k];
                else if (col >= 64 && col < 64 + RR)
                    v = re[(col - 64) * OC + k];
            }
            o[e] = f2bf(v);
        }
        ((bf16x8*)wsB2)[t] = o;
        return;
    }

    // ---- conv: GEMM + maxpool + bias + tanh -> feat bf16 ----
    int cblk = bid - (first ? PACK2B : 0);
    int lane = tid & 63, wave = tid >> 6;
    int oq = wave >> 1, th = wave & 1;
    int lr = lane & 15, lh = lane >> 4;

    const char* gx = (const char*)(xg + (size_t)cblk * (XROWSG * XPAD));
    char* lx = (char*)xs;
    #pragma unroll
    for (int i = 0; i < 3; ++i) {
        int off = i * 8192 + wave * 1024 + lane * 16;
        if (off < XSBYTES) gload_lds16(gx + off, lx + i * 8192 + wave * 1024);
    }
    __syncthreads();

    f32x4 acc[4][4];
    #pragma unroll
    for (int a = 0; a < 4; ++a)
        #pragma unroll
        for (int b = 0; b < 4; ++b) acc[a][b] = (f32x4){0.f, 0.f, 0.f, 0.f};

    const bf16x8* wb = (const bf16x8*)wsB;
    #pragma unroll
    for (int ks = 0; ks < 6; ++ks) {
        bf16x8 bfrag[4];
        #pragma unroll
        for (int nt = 0; nt < 4; ++nt)
            bfrag[nt] = wb[((oq * 6 + ks) * 4 + nt) * 64 + lane];
        int k = ks * 32 + lh * 8;
        int kh = k >> 6, d = k & 63;
        #pragma unroll
        for (int mt = 0; mt < 4; ++mt) {
            int xrow = th * 64 + mt * 16 + lr + kh;
            bf16x8 af = *(const bf16x8*)&xs[xrow * XPAD + d];
            #pragma unroll
            for (int nt = 0; nt < 4; ++nt)
                acc[mt][nt] = __builtin_amdgcn_mfma_f32_16x16x32_bf16(af, bfrag[nt], acc[mt][nt], 0, 0, 0);
        }
    }

    #pragma unroll
    for (int nt = 0; nt < 4; ++nt) {
        float mx = -1e30f;
        #pragma unroll
        for (int mt = 0; mt < 4; ++mt) {
            #pragma unroll
            for (int r = 0; r < 4; ++r) {
                int t = th * 64 + mt * 16 + lh * 4 + r;
                if (t < 122) mx = fmaxf(mx, acc[mt][nt][r]);
            }
        }
        mx = fmaxf(mx, __shfl_xor(mx, 16));
        mx = fmaxf(mx, __shfl_xor(mx, 32));
        if (lane < 16) sm[th][oq * 64 + nt * 16 + lr] = mx;
    }
    __syncthreads();
    if (tid < KP2) {
        int sid = s0 + cblk;
        float v = (tid < OC) ? tanhf(fmaxf(sm[0][tid], sm[1][tid]) + cb[tid]) : 0.f;
        feat16[(size_t)sid * FSTRIDE + tid] = __float2bfloat16(v);
    }
}

// ================= kernel C: per-bag attention + logits + log-softmax + max =================
__global__ __launch_bounds__(512) void bag_kernel(
    const __hip_bfloat16* __restrict__ feat16, const __hip_bfloat16* __restrict__ wsB2,
    const float* __restrict__ rb, float* __restrict__ out)
{
    __shared__ __hip_bfloat16 fA[MM * FSTRIDE];
    __shared__ float scg[MM][132];
    __shared__ float att[RR][17];
    __shared__ float lg[RR * 56];
    __shared__ float lse[RR];
    int b = blockIdx.x, tid = threadIdx.x;
    int lane = tid & 63, wave = tid >> 6;
    int lr = lane & 15, lh = lane >> 4;

    const char* gf = (const char*)(feat16 + (size_t)b * MM * FSTRIDE);
    char* lf = (char*)fA;
    #pragma unroll
    for (int i = 0; i < 2; ++i) {
        int off = i * 8192 + wave * 1024 + lane * 16;
        if (off < MM * FSTRIDE * 2) gload_lds16(gf + off, lf + i * 8192 + wave * 1024);
    }
    __syncthreads();

    f32x4 acc = (f32x4){0.f, 0.f, 0.f, 0.f};
    const bf16x8* wb2 = (const bf16x8*)wsB2;
    #pragma unroll
    for (int ks = 0; ks < 8; ++ks) {
        bf16x8 bfrag = wb2[(ks * 8 + wave) * 64 + lane];
        int k = ks * 32 + lh * 8;
        bf16x8 af = *(const bf16x8*)((const char*)fA + lr * (FSTRIDE * 2) + k * 2);
        acc = __builtin_amdgcn_mfma_f32_16x16x32_bf16(af, bfrag, acc, 0, 0, 0);
    }
    #pragma unroll
    for (int r = 0; r < 4; ++r) scg[lh * 4 + r][wave * 16 + lr] = acc[r];
    __syncthreads();

    if (tid < RR) {
        float mx = -1e30f;
        #pragma unroll
        for (int m = 0; m < MM; ++m) mx = fmaxf(mx, scg[m][tid]);
        float s = 0.f, e[MM];
        #pragma unroll
        for (int m = 0; m < MM; ++m) { e[m] = expf(scg[m][tid] - mx); s += e[m]; }
        float inv = 1.f / s;
        #pragma unroll
        for (int m = 0; m < MM; ++m) att[tid][m] = e[m] * inv;
    }
    __syncthreads();

    for (int idx = tid; idx < RR * RR; idx += 512) {
        int r = idx % RR, s2 = idx / RR;
        float a = 0.f;
        #pragma unroll
        for (int m = 0; m < MM; ++m) a += att[r][m] * scg[m][64 + s2];
        lg[r * 56 + s2] = 0.5f * a + rb[s2];
    }
    __syncthreads();

    if (tid < RR) {
        float mx = -1e30f;
        for (int s2 = 0; s2 < RR; ++s2) mx = fmaxf(mx, lg[tid * 56 + s2]);
        float s = 0.f;
        for (int s2 = 0; s2 < RR; ++s2) s += expf(lg[tid * 56 + s2] - mx);
        lse[tid] = mx + logf(s);
    }
    __syncthreads();

    if (tid < RR) {
        float mx = -1e30f;
        for (int r = 0; r < RR; ++r) mx = fmaxf(mx, lg[r * 56 + tid] - lse[r]);
        out[b * RR + tid] = mx;
    }
}

extern "C" void kernel_launch(void* const* d_in, const int* in_sizes, int n_in,
                              void* d_out, int out_size, void* d_ws, size_t ws_size,
                              hipStream_t stream) {
    const int* wid   = (const int*)d_in[0];
    const int* p1    = (const int*)d_in[1];
    const int* p2    = (const int*)d_in[2];
    const float* w2v = (const float*)d_in[3];
    const float* pe  = (const float*)d_in[4];
    const float* cw  = (const float*)d_in[5];
    const float* cb  = (const float*)d_in[6];
    const float* re  = (const float*)d_in[7];
    const float* rb  = (const float*)d_in[8];
    const float* attW= (const float*)d_in[9];
    float* out = (float*)d_out;

    // ws layout
    float* qf            = (float*)d_ws;                                 // 2*53*230*4 = 97,520
    __hip_bfloat16* wsB  = (__hip_bfloat16*)((char*)d_ws + 98304);       // 98,304
    __hip_bfloat16* wsB2 = (__hip_bfloat16*)((char*)d_ws + 196608);      // 65,536
    __hip_bfloat16* f16  = (__hip_bfloat16*)((char*)d_ws + 262144);      // 2048*280*2 = 1,146,880
    char* xws            = (char*)d_ws + 1409024;

    size_t avail = (ws_size > 1409024) ? ws_size - 1409024 : 0;
    int chunk = (int)(avail / XSBYTES);
    if (chunk > NBAG * MM) chunk = NBAG * MM;
    if (chunk < 4) chunk = 4;

    int first = 1;
    for (int s0 = 0; s0 < NBAG * MM; s0 += chunk) {
        int n = NBAG * MM - s0; if (n > chunk) n = chunk;
        int gA = (first ? (PREPB + QBLOCKS) : 0) + (n + 3) / 4;
        kernelA<<<gA, 512, 0, stream>>>(wid, p1, p2, w2v, pe, cw, attW, re,
                                        wsB, qf, (__hip_bfloat16*)xws, n, s0, first);
        int gB = (first ? PACK2B : 0) + n;
        kernelB<<<gB, 512, 0, stream>>>((const __hip_bfloat16*)xws, wsB, cb,
                                        qf, re, wsB2, f16, s0, first);
        first = 0;
    }
    bag_kernel<<<NBAG, 512, 0, stream>>>(f16, wsB2, rb, out);
}